// Round 16
// baseline (562.055 us; speedup 1.0000x reference)
//
#include <hip/hip_runtime.h>
#include <hip/hip_bf16.h>

// AutoFormer forward. B=32 S=512 IN=256 D=512 H=8 L=2 DFF=2048 NT=424 K=25
#define S_LEN 512
#define D_DIM 512
#define B_DIM 32
#define IN_DIM 256
#define DFF_DIM 2048
#define NT_DIM 424

static constexpr size_t SZ = (size_t)B_DIM * S_LEN * D_DIM; // 8388608

using s8v = __attribute__((ext_vector_type(8))) short;
using f4v = __attribute__((ext_vector_type(4))) float;
typedef unsigned short ushortT;

__device__ __forceinline__ ushortT f2bf(float f) {
  unsigned u = __float_as_uint(f);
  u += 0x7FFFu + ((u >> 16) & 1u);   // RNE
  return (ushortT)(u >> 16);
}
__device__ __forceinline__ float bf2f(ushortT h) {
  return __uint_as_float(((unsigned)h) << 16);
}

// gelu(tanh approx) == x * sigmoid(2*0.7978845608*(x+0.044715x^3)) exactly
__device__ __forceinline__ float gelu_fast(float x) {
  float a = 1.5957691216057308f * (x + 0.044715f * x * x * x);
  return x / (1.f + __expf(-a));
}

__device__ __forceinline__ float2 cadd(float2 a, float2 b) { return float2{a.x + b.x, a.y + b.y}; }
__device__ __forceinline__ float2 csub(float2 a, float2 b) { return float2{a.x - b.x, a.y - b.y}; }
__device__ __forceinline__ float2 cmul(float2 a, float2 b) {
  return float2{a.x * b.x - a.y * b.y, a.x * b.y + a.y * b.x};
}
__device__ __forceinline__ float2 mni(float2 a) { return float2{a.y, -a.x}; } // *(-i)

// 8-point DFT, natural order in/out, e^{-2πi/8} convention.
__device__ __forceinline__ void dft8(float2 a[8]) {
  float2 t0 = cadd(a[0], a[4]), t4 = csub(a[0], a[4]);
  float2 t1 = cadd(a[1], a[5]), t5 = csub(a[1], a[5]);
  float2 t2 = cadd(a[2], a[6]), t6 = csub(a[2], a[6]);
  float2 t3 = cadd(a[3], a[7]), t7 = csub(a[3], a[7]);
  float2 u0 = cadd(t0, t2), u2 = csub(t0, t2);
  float2 u1 = cadd(t1, t3), u3 = csub(t1, t3);
  const float C = 0.70710678118654752f;
  float2 s5 = float2{C * (t5.x + t5.y), C * (t5.y - t5.x)};
  float2 s6 = mni(t6);
  float2 s7 = float2{C * (t7.y - t7.x), -C * (t7.x + t7.y)};
  float2 v0 = cadd(t4, s6), v2 = csub(t4, s6);
  float2 v1 = cadd(s5, s7), v3 = csub(s5, s7);
  a[0] = cadd(u0, u1); a[4] = csub(u0, u1);
  a[2] = cadd(u2, mni(u3)); a[6] = csub(u2, mni(u3));
  a[1] = cadd(v0, v1); a[5] = csub(v0, v1);
  a[3] = cadd(v2, mni(v3)); a[7] = csub(v2, mni(v3));
}

// ---------------------------------------------------------------------------
// All weight conversions + x conversion in ONE dispatch (z picks the work).
// z=0 embed, z=1..8 qkvo, z=9,10 ffn1, z=11,12 ffn2 (transposed bf16),
// z=13 flat x fp32 -> bf16.
// ---------------------------------------------------------------------------
__global__ __launch_bounds__(256) void conv_all(
    const float* __restrict__ embed_w, const float* __restrict__ qkvo_w,
    const float* __restrict__ ffn_w1, const float* __restrict__ ffn_w2,
    const float* __restrict__ xf, ushortT* __restrict__ xb,
    ushortT* __restrict__ embed_wt, ushortT* __restrict__ qkvo_wt,
    ushortT* __restrict__ ffn1_wt, ushortT* __restrict__ ffn2_wt)
{
  __shared__ float T[32][33];
  const int z = blockIdx.z;
  const int tid = threadIdx.x;

  if (z == 13) {   // flat convert x: 1024 blocks x 4096 floats
    const size_t base = ((size_t)blockIdx.y * 16 + blockIdx.x) * 4096;
#pragma unroll
    for (int p = 0; p < 4; ++p) {
      size_t i = base + (size_t)p * 1024 + tid * 4;
      float4 v = *(const float4*)&xf[i];
      ushortT o[4] = {f2bf(v.x), f2bf(v.y), f2bf(v.z), f2bf(v.w)};
      *(uint2*)&xb[i] = *(const uint2*)o;
    }
    return;
  }

  const float* W; ushortT* Wt; int Kp, N;
  if (z == 0)       { W = embed_w; Wt = embed_wt; Kp = 256; N = 512; }
  else if (z <= 8)  { int i = z - 1; W = qkvo_w + (size_t)i * 512 * 512;
                      Wt = qkvo_wt + (size_t)i * 512 * 512; Kp = 512; N = 512; }
  else if (z <= 10) { int l = z - 9; W = ffn_w1 + (size_t)l * 512 * 2048;
                      Wt = ffn1_wt + (size_t)l * 2048 * 512; Kp = 512; N = 2048; }
  else              { int l = z - 11; W = ffn_w2 + (size_t)l * 2048 * 512;
                      Wt = ffn2_wt + (size_t)l * 512 * 2048; Kp = 2048; N = 512; }
  int k0, n0;
  if (z >= 11) { k0 = blockIdx.y * 32; n0 = blockIdx.x * 32; }
  else         { k0 = blockIdx.x * 32; n0 = blockIdx.y * 32; }
  if (k0 >= Kp || n0 >= N) return;

  const int col = tid & 31, r8 = tid >> 5;
#pragma unroll
  for (int it = 0; it < 4; ++it) {
    int row = r8 + it * 8;
    T[row][col] = W[(size_t)(k0 + row) * N + n0 + col];
  }
  __syncthreads();
  const int nl = tid >> 3, kq = tid & 7;
#pragma unroll
  for (int j = 0; j < 4; ++j) {
    int kl = kq * 4 + j;
    Wt[(size_t)(n0 + nl) * Kp + k0 + kl] = f2bf(T[kl][nl]);
  }
}

// ---------------------------------------------------------------------------
// bf16 MFMA GEMM, 3-buffer circular pipeline, counted vmcnt + raw s_barrier.
// RES: 0 none, 2 bf16 res (resb). OUT: 1 fp32+bf16, 2 bf16 only,
// 3 = fused QKV (N=1536): Q/K fp16T [b][c][s], V bf16 plain via Cb.
// Low-precision outputs go through an LDS transpose tile (union w/ staging).
// ---------------------------------------------------------------------------
template<int ACT, int RES, int OUT>
__global__ __launch_bounds__(256) void gemm_bf16(
    const ushortT* __restrict__ A, const ushortT* __restrict__ Wt,
    const float* __restrict__ bias, const ushortT* __restrict__ resb,
    float* __restrict__ C, ushortT* __restrict__ Cb,
    ushortT* __restrict__ Qh, ushortT* __restrict__ Kh, int M, int Kp, int N)
{
  __shared__ __align__(16) ushortT smem[24576];
  ushortT* Tt = smem;

  const int tid = threadIdx.x;
  const int lane = tid & 63, wid = tid >> 6;
  const int fr = lane & 15, kq = lane >> 4;
  const int wr = wid >> 1, wc = wid & 1;

  const int nwg = gridDim.x * gridDim.y;
  const int bid = blockIdx.y * gridDim.x + blockIdx.x;
  const int swz = (bid & 7) * (nwg >> 3) + (bid >> 3);
  const int bx = swz % gridDim.x, by = swz / gridDim.x;
  const int m0 = by * 128, n0 = bx * 128;

  int srow[2], skq[2];
#pragma unroll
  for (int t = 0; t < 2; ++t) {
    int ch = wid * 2 + t;
    int row = ch * 16 + (lane >> 2);
    int kql = lane & 3;
    srow[t] = row;
    skq[t] = kql ^ ((row >> 1) & 3);
  }

  int aoff[4], boff[4];
#pragma unroll
  for (int i = 0; i < 4; ++i) {
    int ra = wr * 64 + i * 16 + fr;
    aoff[i] = ra * 32 + ((kq ^ ((ra >> 1) & 3)) << 3);
    int rb = wc * 64 + i * 16 + fr;
    boff[i] = rb * 32 + ((kq ^ ((rb >> 1) & 3)) << 3);
  }

  auto STAGE = [&](int buf, int k0) {
#pragma unroll
    for (int t = 0; t < 2; ++t) {
      const ushortT* as = A + (size_t)(m0 + srow[t]) * Kp + k0 + skq[t] * 8;
      __builtin_amdgcn_global_load_lds(
          (const __attribute__((address_space(1))) unsigned int*)as,
          (__attribute__((address_space(3))) unsigned int*)&smem[buf * 4096 + (wid * 2 + t) * 512],
          16, 0, 0);
      const ushortT* wsrc = Wt + (size_t)(n0 + srow[t]) * Kp + k0 + skq[t] * 8;
      __builtin_amdgcn_global_load_lds(
          (const __attribute__((address_space(1))) unsigned int*)wsrc,
          (__attribute__((address_space(3))) unsigned int*)&smem[12288 + buf * 4096 + (wid * 2 + t) * 512],
          16, 0, 0);
    }
  };

  f4v acc[4][4] = {};
  STAGE(0, 0);
  if (Kp > 32) STAGE(1, 32);
  int cur = 0, nxt = 2;

  for (int k0 = 0; k0 < Kp; k0 += 32) {
    if (k0 + 32 < Kp) {
      asm volatile("s_waitcnt vmcnt(4)" ::: "memory");
    } else {
      asm volatile("s_waitcnt vmcnt(0)" ::: "memory");
    }
    __builtin_amdgcn_s_barrier();
    __builtin_amdgcn_sched_barrier(0);
    if (k0 + 64 < Kp) {
      STAGE(nxt, k0 + 64);
      nxt = (nxt == 2) ? 0 : nxt + 1;
    }
    s8v af[4], bfv[4];
    const int ab = cur * 4096, wb = 12288 + cur * 4096;
#pragma unroll
    for (int i = 0; i < 4; ++i) {
      af[i]  = *(const s8v*)&smem[ab + aoff[i]];
      bfv[i] = *(const s8v*)&smem[wb + boff[i]];
    }
#pragma unroll
    for (int i = 0; i < 4; ++i)
#pragma unroll
      for (int j = 0; j < 4; ++j)
        acc[i][j] = __builtin_amdgcn_mfma_f32_16x16x32_bf16(af[i], bfv[j], acc[i][j], 0, 0, 0);
    cur = (cur == 2) ? 0 : cur + 1;
  }

  // ---- epilogue (C/D layout: col=lane&15, row=(lane>>4)*4+reg) ----
  if (OUT == 3 && n0 < 1024) {
    __syncthreads();
#pragma unroll
    for (int j = 0; j < 4; ++j) {
      const int c = wc * 64 + j * 16 + fr;
      const float bv = bias[n0 + c];
#pragma unroll
      for (int i = 0; i < 4; ++i)
#pragma unroll
        for (int r = 0; r < 4; ++r) {
          const int s = wr * 64 + i * 16 + kq * 4 + r;
          _Float16 hh = (_Float16)(acc[i][j][r] + bv);
          Tt[c * 132 + s] = __builtin_bit_cast(ushortT, hh);
        }
    }
    __syncthreads();
    ushortT* dstM = (n0 < 512) ? Qh : Kh;
    const int cg0 = n0 & 511;
    const int bb = m0 >> 9, ss0 = m0 & 511;
    const int g = tid >> 4, ln = tid & 15;
#pragma unroll
    for (int p = 0; p < 8; ++p) {
      const int c = p * 16 + g;
      uint4 v = *(const uint4*)&Tt[c * 132 + ln * 8];
      *(uint4*)&dstM[((size_t)bb * 512 + cg0 + c) * 512 + ss0 + ln * 8] = v;
    }
  } else {
    constexpr bool WB16 = (OUT != 0);
    const int nb  = (OUT == 3) ? 512 : N;
    const int cb0 = (OUT == 3) ? (n0 - 1024) : n0;
    if (WB16) __syncthreads();
#pragma unroll
    for (int j = 0; j < 4; ++j) {
      const int lc = wc * 64 + j * 16 + fr;
      const int gc = n0 + lc;
      const float bv = bias[gc];
#pragma unroll
      for (int i = 0; i < 4; ++i)
#pragma unroll
        for (int r = 0; r < 4; ++r) {
          const int lr = wr * 64 + i * 16 + kq * 4 + r;
          const int gr = m0 + lr;
          float v = acc[i][j][r] + bv;
          if (RES == 2) v += bf2f(resb[(size_t)gr * N + gc]);
          if (ACT == 1) v = gelu_fast(v);
          if (OUT == 1) C[(size_t)gr * N + gc] = v;
          if (WB16) Tt[lr * 132 + lc] = f2bf(v);
        }
    }
    if (WB16) {
      __syncthreads();
      const int g = tid >> 4, ln = tid & 15;
#pragma unroll
      for (int p = 0; p < 8; ++p) {
        const int row = p * 16 + g;
        uint4 v = *(const uint4*)&Tt[row * 132 + ln * 8];
        *(uint4*)&Cb[(size_t)(m0 + row) * nb + cb0 + ln * 8] = v;
      }
    }
  }
}

// ---------------------------------------------------------------------------
// FFT auto-correlation. 8 channels/block, 512 threads; wave = channel.
// ---------------------------------------------------------------------------
__global__ __launch_bounds__(512) void autocorr_fft(
    const ushortT* __restrict__ Qh, const ushortT* __restrict__ Kh,
    const ushortT* __restrict__ Vb, ushortT* __restrict__ Ob)
{
  __shared__ float2 zs[8 * 578];
  const int tid = threadIdx.x;
  const int b  = blockIdx.x >> 6;
  const int c0 = (blockIdx.x & 63) << 3;
  const int ch = tid >> 6;
  const int t  = tid & 63;
  float2* zc = &zs[ch * 578];

  {
    const ushortT* Qg = Qh + ((size_t)b * 512 + c0 + ch) * 512 + t * 8;
    const ushortT* Kg = Kh + ((size_t)b * 512 + c0 + ch) * 512 + t * 8;
    uint4 qv = *(const uint4*)Qg;
    uint4 kv = *(const uint4*)Kg;
    const ushortT* qp = (const ushortT*)&qv;
    const ushortT* kp = (const ushortT*)&kv;
    const int base = 9 * t;
#pragma unroll
    for (int j = 0; j < 8; ++j) {
      zc[base + j] = float2{(float)__builtin_bit_cast(_Float16, qp[j]),
                            (float)__builtin_bit_cast(_Float16, kp[j])};
    }
  }
  __syncthreads();

  float2 a[8];
  auto stage_fn = [&](int stage, bool do_scatter) {
#pragma unroll
    for (int r = 0; r < 8; ++r) { int ci = t + 64 * r; a[r] = zc[ci + (ci >> 3)]; }
    dft8(a);
    if (stage < 2) {
      float angle = (stage == 0) ? (-6.283185307179586f / 512.f) * (float)t
                                 : (-6.283185307179586f / 64.f) * (float)(t >> 3);
      float sn, cs;
      __sincosf(angle, &sn, &cs);
      float2 w = float2{cs, sn}, wp = w;
      a[1] = cmul(a[1], wp);
#pragma unroll
      for (int r = 2; r < 8; ++r) { wp = cmul(wp, w); a[r] = cmul(a[r], wp); }
    }
    if (!do_scatter) return;
    __syncthreads();
#pragma unroll
    for (int r = 0; r < 8; ++r) {
      int ci = (stage == 0) ? 8 * t + r
             : (stage == 1) ? (t & 7) + 64 * (t >> 3) + 8 * r
                            : t + 64 * r;
      zc[ci + (ci >> 3)] = a[r];
    }
    __syncthreads();
  };

  stage_fn(0, true); stage_fn(1, true); stage_fn(2, true);

  float2 Zk[8], Zm[8];
#pragma unroll
  for (int r = 0; r < 8; ++r) {
    int k = t + 64 * r, mk = (512 - k) & 511;
    Zk[r] = zc[k + (k >> 3)];
    Zm[r] = zc[mk + (mk >> 3)];
  }
  __syncthreads();
  const float S = 0.00048828125f;   // 0.25/512
#pragma unroll
  for (int r = 0; r < 8; ++r) {
    int k = t + 64 * r;
    float x1 = Zk[r].x, y1 = Zk[r].y, x2 = Zm[r].x, y2 = Zm[r].y;
    float sx = x1 + x2, dx = x1 - x2, sy = y1 + y2, dy = y1 - y2;
    float pre = sx * sy - dy * dx;
    float pim = sx * dx + dy * sy;
    zc[k + (k >> 3)] = float2{pre * S, -pim * S};
  }
  __syncthreads();

  stage_fn(0, true); stage_fn(1, true); stage_fn(2, false);

  float corr[8];
#pragma unroll
  for (int r = 0; r < 8; ++r) corr[r] = a[r].x;
  float mx = corr[0];
#pragma unroll
  for (int r = 1; r < 8; ++r) mx = fmaxf(mx, corr[r]);
#pragma unroll
  for (int o = 1; o < 64; o <<= 1) mx = fmaxf(mx, __shfl_xor(mx, o));
  float ex[8], sum = 0.f;
#pragma unroll
  for (int r = 0; r < 8; ++r) { ex[r] = __expf(corr[r] - mx); sum += ex[r]; }
#pragma unroll
  for (int o = 1; o < 64; o <<= 1) sum += __shfl_xor(sum, o);
  const float inv = 1.f / sum;

  __syncthreads();
  float* wl = (float*)zc;
#pragma unroll
  for (int r = 0; r < 8; ++r) wl[t + 64 * r] = ex[r] * inv;
  __syncthreads();

  const float* wall = (const float*)zs;
  const size_t base = (size_t)b * S_LEN * D_DIM + c0;
  for (int i = tid; i < 4096; i += 512) {
    int s = i >> 3, cc = i & 7;
    float wv = wall[cc * 1156 + s];
    size_t ad = base + (size_t)s * D_DIM + cc;
    Ob[ad] = f2bf(wv * bf2f(Vb[ad]));
  }
}

// ---------------------------------------------------------------------------
// out = y - movavg(y,25), bf16 in/out, sliding-window; optional fused mean.
// LDS rows padded to 33 floats -> conflict-free writes and reads.
// ---------------------------------------------------------------------------
template<int MEAN>
__global__ __launch_bounds__(256) void movavg_bf16(
    const ushortT* __restrict__ y, ushortT* __restrict__ outb,
    float* __restrict__ hm)
{
  __shared__ float ys[512 * 33];
  const int tid = threadIdx.x;
  const int b = blockIdx.y, d0 = blockIdx.x * 32;
  const ushortT* yb = y + (size_t)b * S_LEN * D_DIM + d0;

#pragma unroll
  for (int p = 0; p < 8; ++p) {
    int i = p * 256 + tid;            // 8-bf16 chunk index over [512][4]
    int s = i >> 2, dq = i & 3;
    uint4 v = *(const uint4*)(yb + (size_t)s * D_DIM + dq * 8);
    const ushortT* hp = (const ushortT*)&v;
#pragma unroll
    for (int j = 0; j < 8; ++j) ys[s * 33 + dq * 8 + j] = bf2f(hp[j]);
  }
  __syncthreads();

  const int d = tid & 31, sg = tid >> 5;
  const int s0 = sg * 64;
  int lo = max(s0 - 12, 0), hi = min(s0 + 13, S_LEN);
  float sum = 0.f;
  for (int t = lo; t < hi; ++t) sum += ys[t * 33 + d];

  float msum = 0.f;
  const size_t gb = (size_t)b * S_LEN * D_DIM + d0 + d;
  for (int i = 0; i < 64; ++i) {
    const int s = s0 + i;
    float val = ys[s * 33 + d] - sum / (float)(hi - lo);
    outb[gb + (size_t)s * D_DIM] = f2bf(val);
    if (MEAN) msum += val;
    int add = s + 13;
    if (add < S_LEN) { sum += ys[add * 33 + d]; hi = add + 1; }
    int rem = s - 12;
    if (rem >= 0) { sum -= ys[rem * 33 + d]; lo = rem + 1; }
  }
  if (MEAN) atomicAdd(&hm[b * D_DIM + d0 + d], msum * (1.f / (float)S_LEN));
}

// ---------------------------------------------------------------------------
// Fused head: block b -> p1[b,:] = relu(hm[b,:]@W1+b1); out[b,:] = p1@W2+b2
// ---------------------------------------------------------------------------
__global__ __launch_bounds__(256) void proj_head(
    const float* __restrict__ hm, const float* __restrict__ W1,
    const float* __restrict__ b1, const float* __restrict__ W2,
    const float* __restrict__ b2, float* __restrict__ out)
{
  __shared__ float hs[512];
  __shared__ float ps[256];
  const int b = blockIdx.x, tid = threadIdx.x;
  if (tid < 128)
    *(float4*)&hs[tid * 4] = *(const float4*)&hm[(size_t)b * 512 + tid * 4];
  __syncthreads();

  float acc = b1[tid];
#pragma unroll 4
  for (int k = 0; k < 512; ++k)
    acc = fmaf(hs[k], W1[(size_t)k * 256 + tid], acc);
  ps[tid] = fmaxf(acc, 0.f);
  __syncthreads();

  for (int n = tid; n < NT_DIM; n += 256) {
    float a2 = b2[n];
#pragma unroll 4
    for (int k = 0; k < 256; ++k)
      a2 = fmaf(ps[k], W2[(size_t)k * NT_DIM + n], a2);
    out[(size_t)b * NT_DIM + n] = a2;
  }
}

// ---------------------------------------------------------------------------
extern "C" void kernel_launch(void* const* d_in, const int* in_sizes, int n_in,
                              void* d_out, int out_size, void* d_ws, size_t ws_size,
                              hipStream_t stream)
{
  const float* x       = (const float*)d_in[0];
  const float* embed_w = (const float*)d_in[1];
  const float* embed_b = (const float*)d_in[2];
  const float* qkvo_w  = (const float*)d_in[3];
  const float* qkvo_b  = (const float*)d_in[4];
  const float* ffn_w1  = (const float*)d_in[5];
  const float* ffn_b1  = (const float*)d_in[6];
  const float* ffn_w2  = (const float*)d_in[7];
  const float* ffn_b2  = (const float*)d_in[8];
  const float* proj_w1 = (const float*)d_in[9];
  const float* proj_b1 = (const float*)d_in[10];
  const float* proj_w2 = (const float*)d_in[11];
  const float* proj_b2 = (const float*)d_in[12];
  float* out = (float*)d_out;

  float* ws = (float*)d_ws;
  // slots: 0 = Vb bf16 / Hb half; 1 = Hb half; 2 = xb -> QKh fp16T -> Yb bf16;
  //        3 = Xb bf16 trunk (x / h)
  float* Bv = ws;
  float* Bq = ws + 2 * SZ;
  float* Bk = ws + 3 * SZ;
  ushortT* Sb = (ushortT*)(ws + 4 * SZ);            // bf16 scratch (x1 / attn)
  ushortT* Wb = (ushortT*)(ws + 4 * SZ + SZ / 2);   // bf16 weights
  ushortT* embed_wt = Wb;                            // [512][256]
  ushortT* qkvo_wt  = embed_wt + (size_t)512 * 256;  // 8 x [512][512]
  ushortT* ffn1_wt  = qkvo_wt + (size_t)8 * 512 * 512;   // 2 x [2048][512]
  ushortT* ffn2_wt  = ffn1_wt + (size_t)2 * 2048 * 512;  // 2 x [512][2048]
  float* hm = (float*)(ffn2_wt + (size_t)2 * 512 * 2048); // [32][512]
  ushortT* Hb  = (ushortT*)Bv;   // FFN hidden bf16 [16384][2048] (slots 0+1)
  ushortT* Vb  = (ushortT*)Bv;   // V bf16 [16384][512]
  ushortT* xb  = (ushortT*)Bq;   // x bf16 during embed
  ushortT* QKh = (ushortT*)Bq;   // Qh [0,SZ) + Kh [SZ,2SZ) fp16T
  ushortT* Yb  = (ushortT*)Bq;   // y bf16 (after QKh dead)
  ushortT* Xb  = (ushortT*)Bk;   // trunk x bf16

  dim3 blk(256);

  hipMemsetAsync(hm, 0, 16384 * sizeof(float), stream);

  // weight conversions + x->bf16, one dispatch
  conv_all<<<dim3(16, 64, 14), blk, 0, stream>>>(
      embed_w, qkvo_w, ffn_w1, ffn_w2, x, xb,
      embed_wt, qkvo_wt, ffn1_wt, ffn2_wt);

  // embed: Xb(bf16) = x @ We + be
  gemm_bf16<0, 0, 2><<<dim3(4, 128), blk, 0, stream>>>(
      xb, embed_wt, embed_b, nullptr, nullptr, Xb, nullptr, nullptr,
      16384, IN_DIM, D_DIM);

  for (int l = 0; l < 2; ++l) {
    const ushortT* qw = qkvo_wt + (size_t)l * 4 * 512 * 512;
    const float* qb = qkvo_b + (size_t)l * 4 * 512;
    // fused QKV: Q -> QKh (fp16T), K -> QKh+SZ (fp16T), V -> Vb (bf16 plain)
    gemm_bf16<0, 0, 3><<<dim3(12, 128), blk, 0, stream>>>(
        Xb, qw, qb, nullptr, nullptr, Vb, QKh, QKh + SZ, 16384, 512, 1536);
    autocorr_fft<<<dim3(B_DIM * 64), dim3(512), 0, stream>>>(QKh, QKh + SZ, Vb, Sb);
    // y(bf16) = attn @ Wo + bo + x (bf16 res)  (QKh dead -> Yb)
    gemm_bf16<0, 2, 2><<<dim3(4, 128), blk, 0, stream>>>(
        Sb, qw + (size_t)3 * 512 * 512, qb + 1536, Xb, nullptr, Yb,
        nullptr, nullptr, 16384, 512, 512);
    // x1 = y - movavg(y) -> Sb
    movavg_bf16<0><<<dim3(16, 32), blk, 0, stream>>>(Yb, Sb, nullptr);
    // FFN (hidden bf16 overlays slots 0+1; V dead)
    gemm_bf16<1, 0, 2><<<dim3(16, 128), blk, 0, stream>>>(
        Sb, ffn1_wt + (size_t)l * 2048 * 512, ffn_b1 + (size_t)l * DFF_DIM,
        nullptr, nullptr, Hb, nullptr, nullptr, 16384, 512, 2048);
    gemm_bf16<0, 2, 2><<<dim3(4, 128), blk, 0, stream>>>(
        Hb, ffn2_wt + (size_t)l * 512 * 2048, ffn_b2 + (size_t)l * D_DIM,
        Sb, nullptr, Yb, nullptr, nullptr, 16384, 2048, 512);
    // x_next = y2 - movavg(y2) -> Xb (+ fused mean on last layer)
    if (l == 1)
      movavg_bf16<1><<<dim3(16, 32), blk, 0, stream>>>(Yb, Xb, hm);
    else
      movavg_bf16<0><<<dim3(16, 32), blk, 0, stream>>>(Yb, Xb, nullptr);
  }

  proj_head<<<dim3(32), blk, 0, stream>>>(hm, proj_w1, proj_b1,
                                          proj_w2, proj_b2, out);
}

// Round 17
// 504.073 us; speedup vs baseline: 1.1150x; 1.1150x over previous
//
#include <hip/hip_runtime.h>
#include <hip/hip_bf16.h>

// AutoFormer forward. B=32 S=512 IN=256 D=512 H=8 L=2 DFF=2048 NT=424 K=25
#define S_LEN 512
#define D_DIM 512
#define B_DIM 32
#define IN_DIM 256
#define DFF_DIM 2048
#define NT_DIM 424

static constexpr size_t SZ = (size_t)B_DIM * S_LEN * D_DIM; // 8388608

using s8v = __attribute__((ext_vector_type(8))) short;
using f4v = __attribute__((ext_vector_type(4))) float;
typedef unsigned short ushortT;

__device__ __forceinline__ ushortT f2bf(float f) {
  unsigned u = __float_as_uint(f);
  u += 0x7FFFu + ((u >> 16) & 1u);   // RNE
  return (ushortT)(u >> 16);
}
__device__ __forceinline__ float bf2f(ushortT h) {
  return __uint_as_float(((unsigned)h) << 16);
}

// gelu(tanh approx) == x * sigmoid(2*0.7978845608*(x+0.044715x^3)) exactly
__device__ __forceinline__ float gelu_fast(float x) {
  float a = 1.5957691216057308f * (x + 0.044715f * x * x * x);
  return x / (1.f + __expf(-a));
}

__device__ __forceinline__ float2 cadd(float2 a, float2 b) { return float2{a.x + b.x, a.y + b.y}; }
__device__ __forceinline__ float2 csub(float2 a, float2 b) { return float2{a.x - b.x, a.y - b.y}; }
__device__ __forceinline__ float2 cmul(float2 a, float2 b) {
  return float2{a.x * b.x - a.y * b.y, a.x * b.y + a.y * b.x};
}
__device__ __forceinline__ float2 mni(float2 a) { return float2{a.y, -a.x}; } // *(-i)

// 8-point DFT, natural order in/out, e^{-2πi/8} convention.
__device__ __forceinline__ void dft8(float2 a[8]) {
  float2 t0 = cadd(a[0], a[4]), t4 = csub(a[0], a[4]);
  float2 t1 = cadd(a[1], a[5]), t5 = csub(a[1], a[5]);
  float2 t2 = cadd(a[2], a[6]), t6 = csub(a[2], a[6]);
  float2 t3 = cadd(a[3], a[7]), t7 = csub(a[3], a[7]);
  float2 u0 = cadd(t0, t2), u2 = csub(t0, t2);
  float2 u1 = cadd(t1, t3), u3 = csub(t1, t3);
  const float C = 0.70710678118654752f;
  float2 s5 = float2{C * (t5.x + t5.y), C * (t5.y - t5.x)};
  float2 s6 = mni(t6);
  float2 s7 = float2{C * (t7.y - t7.x), -C * (t7.x + t7.y)};
  float2 v0 = cadd(t4, s6), v2 = csub(t4, s6);
  float2 v1 = cadd(s5, s7), v3 = csub(s5, s7);
  a[0] = cadd(u0, u1); a[4] = csub(u0, u1);
  a[2] = cadd(u2, mni(u3)); a[6] = csub(u2, mni(u3));
  a[1] = cadd(v0, v1); a[5] = csub(v0, v1);
  a[3] = cadd(v2, mni(v3)); a[7] = csub(v2, mni(v3));
}

// ---------------------------------------------------------------------------
// All weight conversions + x conversion in ONE dispatch (z picks the work).
// ---------------------------------------------------------------------------
__global__ __launch_bounds__(256) void conv_all(
    const float* __restrict__ embed_w, const float* __restrict__ qkvo_w,
    const float* __restrict__ ffn_w1, const float* __restrict__ ffn_w2,
    const float* __restrict__ xf, ushortT* __restrict__ xb,
    ushortT* __restrict__ embed_wt, ushortT* __restrict__ qkvo_wt,
    ushortT* __restrict__ ffn1_wt, ushortT* __restrict__ ffn2_wt)
{
  __shared__ float T[32][33];
  const int z = blockIdx.z;
  const int tid = threadIdx.x;

  if (z == 13) {   // flat convert x: 1024 blocks x 4096 floats
    const size_t base = ((size_t)blockIdx.y * 16 + blockIdx.x) * 4096;
#pragma unroll
    for (int p = 0; p < 4; ++p) {
      size_t i = base + (size_t)p * 1024 + tid * 4;
      float4 v = *(const float4*)&xf[i];
      ushortT o[4] = {f2bf(v.x), f2bf(v.y), f2bf(v.z), f2bf(v.w)};
      *(uint2*)&xb[i] = *(const uint2*)o;
    }
    return;
  }

  const float* W; ushortT* Wt; int Kp, N;
  if (z == 0)       { W = embed_w; Wt = embed_wt; Kp = 256; N = 512; }
  else if (z <= 8)  { int i = z - 1; W = qkvo_w + (size_t)i * 512 * 512;
                      Wt = qkvo_wt + (size_t)i * 512 * 512; Kp = 512; N = 512; }
  else if (z <= 10) { int l = z - 9; W = ffn_w1 + (size_t)l * 512 * 2048;
                      Wt = ffn1_wt + (size_t)l * 2048 * 512; Kp = 512; N = 2048; }
  else              { int l = z - 11; W = ffn_w2 + (size_t)l * 2048 * 512;
                      Wt = ffn2_wt + (size_t)l * 512 * 2048; Kp = 2048; N = 512; }
  int k0, n0;
  if (z >= 11) { k0 = blockIdx.y * 32; n0 = blockIdx.x * 32; }
  else         { k0 = blockIdx.x * 32; n0 = blockIdx.y * 32; }
  if (k0 >= Kp || n0 >= N) return;

  const int col = tid & 31, r8 = tid >> 5;
#pragma unroll
  for (int it = 0; it < 4; ++it) {
    int row = r8 + it * 8;
    T[row][col] = W[(size_t)(k0 + row) * N + n0 + col];
  }
  __syncthreads();
  const int nl = tid >> 3, kq = tid & 7;
#pragma unroll
  for (int j = 0; j < 4; ++j) {
    int kl = kq * 4 + j;
    Wt[(size_t)(n0 + nl) * Kp + k0 + kl] = f2bf(T[kl][nl]);
  }
}

// ---------------------------------------------------------------------------
// bf16 MFMA GEMM, 3-buffer circular pipeline, counted vmcnt + raw s_barrier.
// RES: 0 none, 2 bf16 res (resb). OUT: 1 fp32+bf16, 2 bf16 only,
// 3 = fused QKV (N=1536): Q/K fp16T [b][c][s], V bf16 plain via Cb.
// ---------------------------------------------------------------------------
template<int ACT, int RES, int OUT>
__global__ __launch_bounds__(256) void gemm_bf16(
    const ushortT* __restrict__ A, const ushortT* __restrict__ Wt,
    const float* __restrict__ bias, const ushortT* __restrict__ resb,
    float* __restrict__ C, ushortT* __restrict__ Cb,
    ushortT* __restrict__ Qh, ushortT* __restrict__ Kh, int M, int Kp, int N)
{
  __shared__ __align__(16) ushortT smem[24576];
  ushortT* Tt = smem;

  const int tid = threadIdx.x;
  const int lane = tid & 63, wid = tid >> 6;
  const int fr = lane & 15, kq = lane >> 4;
  const int wr = wid >> 1, wc = wid & 1;

  const int nwg = gridDim.x * gridDim.y;
  const int bid = blockIdx.y * gridDim.x + blockIdx.x;
  const int swz = (bid & 7) * (nwg >> 3) + (bid >> 3);
  const int bx = swz % gridDim.x, by = swz / gridDim.x;
  const int m0 = by * 128, n0 = bx * 128;

  int srow[2], skq[2];
#pragma unroll
  for (int t = 0; t < 2; ++t) {
    int ch = wid * 2 + t;
    int row = ch * 16 + (lane >> 2);
    int kql = lane & 3;
    srow[t] = row;
    skq[t] = kql ^ ((row >> 1) & 3);
  }

  int aoff[4], boff[4];
#pragma unroll
  for (int i = 0; i < 4; ++i) {
    int ra = wr * 64 + i * 16 + fr;
    aoff[i] = ra * 32 + ((kq ^ ((ra >> 1) & 3)) << 3);
    int rb = wc * 64 + i * 16 + fr;
    boff[i] = rb * 32 + ((kq ^ ((rb >> 1) & 3)) << 3);
  }

  auto STAGE = [&](int buf, int k0) {
#pragma unroll
    for (int t = 0; t < 2; ++t) {
      const ushortT* as = A + (size_t)(m0 + srow[t]) * Kp + k0 + skq[t] * 8;
      __builtin_amdgcn_global_load_lds(
          (const __attribute__((address_space(1))) unsigned int*)as,
          (__attribute__((address_space(3))) unsigned int*)&smem[buf * 4096 + (wid * 2 + t) * 512],
          16, 0, 0);
      const ushortT* wsrc = Wt + (size_t)(n0 + srow[t]) * Kp + k0 + skq[t] * 8;
      __builtin_amdgcn_global_load_lds(
          (const __attribute__((address_space(1))) unsigned int*)wsrc,
          (__attribute__((address_space(3))) unsigned int*)&smem[12288 + buf * 4096 + (wid * 2 + t) * 512],
          16, 0, 0);
    }
  };

  f4v acc[4][4] = {};
  STAGE(0, 0);
  if (Kp > 32) STAGE(1, 32);
  int cur = 0, nxt = 2;

  for (int k0 = 0; k0 < Kp; k0 += 32) {
    if (k0 + 32 < Kp) {
      asm volatile("s_waitcnt vmcnt(4)" ::: "memory");
    } else {
      asm volatile("s_waitcnt vmcnt(0)" ::: "memory");
    }
    __builtin_amdgcn_s_barrier();
    __builtin_amdgcn_sched_barrier(0);
    if (k0 + 64 < Kp) {
      STAGE(nxt, k0 + 64);
      nxt = (nxt == 2) ? 0 : nxt + 1;
    }
    s8v af[4], bfv[4];
    const int ab = cur * 4096, wb = 12288 + cur * 4096;
#pragma unroll
    for (int i = 0; i < 4; ++i) {
      af[i]  = *(const s8v*)&smem[ab + aoff[i]];
      bfv[i] = *(const s8v*)&smem[wb + boff[i]];
    }
#pragma unroll
    for (int i = 0; i < 4; ++i)
#pragma unroll
      for (int j = 0; j < 4; ++j)
        acc[i][j] = __builtin_amdgcn_mfma_f32_16x16x32_bf16(af[i], bfv[j], acc[i][j], 0, 0, 0);
    cur = (cur == 2) ? 0 : cur + 1;
  }

  // ---- epilogue (C/D layout: col=lane&15, row=(lane>>4)*4+reg) ----
  if (OUT == 3 && n0 < 1024) {
    __syncthreads();
#pragma unroll
    for (int j = 0; j < 4; ++j) {
      const int c = wc * 64 + j * 16 + fr;
      const float bv = bias[n0 + c];
#pragma unroll
      for (int i = 0; i < 4; ++i)
#pragma unroll
        for (int r = 0; r < 4; ++r) {
          const int s = wr * 64 + i * 16 + kq * 4 + r;
          _Float16 hh = (_Float16)(acc[i][j][r] + bv);
          Tt[c * 132 + s] = __builtin_bit_cast(ushortT, hh);
        }
    }
    __syncthreads();
    ushortT* dstM = (n0 < 512) ? Qh : Kh;
    const int cg0 = n0 & 511;
    const int bb = m0 >> 9, ss0 = m0 & 511;
    const int g = tid >> 4, ln = tid & 15;
#pragma unroll
    for (int p = 0; p < 8; ++p) {
      const int c = p * 16 + g;
      uint4 v = *(const uint4*)&Tt[c * 132 + ln * 8];
      *(uint4*)&dstM[((size_t)bb * 512 + cg0 + c) * 512 + ss0 + ln * 8] = v;
    }
  } else {
    constexpr bool WB16 = (OUT != 0);
    const int nb  = (OUT == 3) ? 512 : N;
    const int cb0 = (OUT == 3) ? (n0 - 1024) : n0;
    if (WB16) __syncthreads();
#pragma unroll
    for (int j = 0; j < 4; ++j) {
      const int lc = wc * 64 + j * 16 + fr;
      const int gc = n0 + lc;
      const float bv = bias[gc];
#pragma unroll
      for (int i = 0; i < 4; ++i)
#pragma unroll
        for (int r = 0; r < 4; ++r) {
          const int lr = wr * 64 + i * 16 + kq * 4 + r;
          const int gr = m0 + lr;
          float v = acc[i][j][r] + bv;
          if (RES == 2) v += bf2f(resb[(size_t)gr * N + gc]);
          if (ACT == 1) v = gelu_fast(v);
          if (OUT == 1) C[(size_t)gr * N + gc] = v;
          if (WB16) Tt[lr * 132 + lc] = f2bf(v);
        }
    }
    if (WB16) {
      __syncthreads();
      const int g = tid >> 4, ln = tid & 15;
#pragma unroll
      for (int p = 0; p < 8; ++p) {
        const int row = p * 16 + g;
        uint4 v = *(const uint4*)&Tt[row * 132 + ln * 8];
        *(uint4*)&Cb[(size_t)(m0 + row) * nb + cb0 + ln * 8] = v;
      }
    }
  }
}

// ---------------------------------------------------------------------------
// FFT auto-correlation. 8 channels/block, 512 threads; wave = channel.
// ---------------------------------------------------------------------------
__global__ __launch_bounds__(512) void autocorr_fft(
    const ushortT* __restrict__ Qh, const ushortT* __restrict__ Kh,
    const ushortT* __restrict__ Vb, ushortT* __restrict__ Ob)
{
  __shared__ float2 zs[8 * 578];
  const int tid = threadIdx.x;
  const int b  = blockIdx.x >> 6;
  const int c0 = (blockIdx.x & 63) << 3;
  const int ch = tid >> 6;
  const int t  = tid & 63;
  float2* zc = &zs[ch * 578];

  {
    const ushortT* Qg = Qh + ((size_t)b * 512 + c0 + ch) * 512 + t * 8;
    const ushortT* Kg = Kh + ((size_t)b * 512 + c0 + ch) * 512 + t * 8;
    uint4 qv = *(const uint4*)Qg;
    uint4 kv = *(const uint4*)Kg;
    const ushortT* qp = (const ushortT*)&qv;
    const ushortT* kp = (const ushortT*)&kv;
    const int base = 9 * t;
#pragma unroll
    for (int j = 0; j < 8; ++j) {
      zc[base + j] = float2{(float)__builtin_bit_cast(_Float16, qp[j]),
                            (float)__builtin_bit_cast(_Float16, kp[j])};
    }
  }
  __syncthreads();

  float2 a[8];
  auto stage_fn = [&](int stage, bool do_scatter) {
#pragma unroll
    for (int r = 0; r < 8; ++r) { int ci = t + 64 * r; a[r] = zc[ci + (ci >> 3)]; }
    dft8(a);
    if (stage < 2) {
      float angle = (stage == 0) ? (-6.283185307179586f / 512.f) * (float)t
                                 : (-6.283185307179586f / 64.f) * (float)(t >> 3);
      float sn, cs;
      __sincosf(angle, &sn, &cs);
      float2 w = float2{cs, sn}, wp = w;
      a[1] = cmul(a[1], wp);
#pragma unroll
      for (int r = 2; r < 8; ++r) { wp = cmul(wp, w); a[r] = cmul(a[r], wp); }
    }
    if (!do_scatter) return;
    __syncthreads();
#pragma unroll
    for (int r = 0; r < 8; ++r) {
      int ci = (stage == 0) ? 8 * t + r
             : (stage == 1) ? (t & 7) + 64 * (t >> 3) + 8 * r
                            : t + 64 * r;
      zc[ci + (ci >> 3)] = a[r];
    }
    __syncthreads();
  };

  stage_fn(0, true); stage_fn(1, true); stage_fn(2, true);

  float2 Zk[8], Zm[8];
#pragma unroll
  for (int r = 0; r < 8; ++r) {
    int k = t + 64 * r, mk = (512 - k) & 511;
    Zk[r] = zc[k + (k >> 3)];
    Zm[r] = zc[mk + (mk >> 3)];
  }
  __syncthreads();
  const float S = 0.00048828125f;   // 0.25/512
#pragma unroll
  for (int r = 0; r < 8; ++r) {
    int k = t + 64 * r;
    float x1 = Zk[r].x, y1 = Zk[r].y, x2 = Zm[r].x, y2 = Zm[r].y;
    float sx = x1 + x2, dx = x1 - x2, sy = y1 + y2, dy = y1 - y2;
    float pre = sx * sy - dy * dx;
    float pim = sx * dx + dy * sy;
    zc[k + (k >> 3)] = float2{pre * S, -pim * S};
  }
  __syncthreads();

  stage_fn(0, true); stage_fn(1, true); stage_fn(2, false);

  float corr[8];
#pragma unroll
  for (int r = 0; r < 8; ++r) corr[r] = a[r].x;
  float mx = corr[0];
#pragma unroll
  for (int r = 1; r < 8; ++r) mx = fmaxf(mx, corr[r]);
#pragma unroll
  for (int o = 1; o < 64; o <<= 1) mx = fmaxf(mx, __shfl_xor(mx, o));
  float ex[8], sum = 0.f;
#pragma unroll
  for (int r = 0; r < 8; ++r) { ex[r] = __expf(corr[r] - mx); sum += ex[r]; }
#pragma unroll
  for (int o = 1; o < 64; o <<= 1) sum += __shfl_xor(sum, o);
  const float inv = 1.f / sum;

  __syncthreads();
  float* wl = (float*)zc;
#pragma unroll
  for (int r = 0; r < 8; ++r) wl[t + 64 * r] = ex[r] * inv;
  __syncthreads();

  const float* wall = (const float*)zs;
  const size_t base = (size_t)b * S_LEN * D_DIM + c0;
  for (int i = tid; i < 4096; i += 512) {
    int s = i >> 3, cc = i & 7;
    float wv = wall[cc * 1156 + s];
    size_t ad = base + (size_t)s * D_DIM + cc;
    Ob[ad] = f2bf(wv * bf2f(Vb[ad]));
  }
}

// ---------------------------------------------------------------------------
// out = y - movavg(y,25), bf16 in/out, sliding-window; optional fused mean.
// ---------------------------------------------------------------------------
template<int MEAN>
__global__ __launch_bounds__(256) void movavg_bf16(
    const ushortT* __restrict__ y, ushortT* __restrict__ outb,
    float* __restrict__ hm)
{
  __shared__ float ys[512 * 33];
  const int tid = threadIdx.x;
  const int b = blockIdx.y, d0 = blockIdx.x * 32;
  const ushortT* yb = y + (size_t)b * S_LEN * D_DIM + d0;

#pragma unroll
  for (int p = 0; p < 8; ++p) {
    int i = p * 256 + tid;            // 8-bf16 chunk index over [512][4]
    int s = i >> 2, dq = i & 3;
    uint4 v = *(const uint4*)(yb + (size_t)s * D_DIM + dq * 8);
    const ushortT* hp = (const ushortT*)&v;
#pragma unroll
    for (int j = 0; j < 8; ++j) ys[s * 33 + dq * 8 + j] = bf2f(hp[j]);
  }
  __syncthreads();

  const int d = tid & 31, sg = tid >> 5;
  const int s0 = sg * 64;
  int lo = max(s0 - 12, 0), hi = min(s0 + 13, S_LEN);
  float sum = 0.f;
  for (int t = lo; t < hi; ++t) sum += ys[t * 33 + d];

  float msum = 0.f;
  const size_t gb = (size_t)b * S_LEN * D_DIM + d0 + d;
  for (int i = 0; i < 64; ++i) {
    const int s = s0 + i;
    float val = ys[s * 33 + d] - sum / (float)(hi - lo);
    outb[gb + (size_t)s * D_DIM] = f2bf(val);
    if (MEAN) msum += val;
    int add = s + 13;
    if (add < S_LEN) { sum += ys[add * 33 + d]; hi = add + 1; }
    int rem = s - 12;
    if (rem >= 0) { sum -= ys[rem * 33 + d]; lo = rem + 1; }
  }
  if (MEAN) atomicAdd(&hm[b * D_DIM + d0 + d], msum * (1.f / (float)S_LEN));
}

// ---------------------------------------------------------------------------
// Head, K-split parallel. proj1_part: p1raw[m][n] += hm[m][kslice]@W1 (no bias)
// grid (8 ntiles, 16 ksplits). proj2_part: out[m][n] += relu(p1raw+b1)@W2
// (+b2 once, from ks==0 blocks). grid (14 ntiles, 8 ksplits).
// ---------------------------------------------------------------------------
__global__ __launch_bounds__(256) void proj1_part(
    const float* __restrict__ hm, const float* __restrict__ W1,
    float* __restrict__ p1raw)
{
  __shared__ float hs[32][33];
  const int tid = threadIdx.x;
  const int n0 = blockIdx.x * 32, k0 = blockIdx.y * 32;
#pragma unroll
  for (int it = 0; it < 4; ++it) {
    int idx = it * 256 + tid;
    int m = idx >> 5, kk = idx & 31;
    hs[m][kk] = hm[(size_t)m * 512 + k0 + kk];
  }
  __syncthreads();
  const int n = tid & 31, mg = tid >> 5;   // 8 groups x 4 rows
  float acc[4] = {};
#pragma unroll 8
  for (int kk = 0; kk < 32; ++kk) {
    float w = W1[(size_t)(k0 + kk) * 256 + n0 + n];
#pragma unroll
    for (int mi = 0; mi < 4; ++mi)
      acc[mi] = fmaf(hs[mg * 4 + mi][kk], w, acc[mi]);
  }
#pragma unroll
  for (int mi = 0; mi < 4; ++mi)
    atomicAdd(&p1raw[(size_t)(mg * 4 + mi) * 256 + n0 + n], acc[mi]);
}

__global__ __launch_bounds__(256) void proj2_part(
    const float* __restrict__ p1raw, const float* __restrict__ b1,
    const float* __restrict__ W2, const float* __restrict__ b2,
    float* __restrict__ out)
{
  __shared__ float ps[32][33];
  const int tid = threadIdx.x;
  const int n0 = blockIdx.x * 32, k0 = blockIdx.y * 32;
#pragma unroll
  for (int it = 0; it < 4; ++it) {
    int idx = it * 256 + tid;
    int m = idx >> 5, kk = idx & 31;
    ps[m][kk] = fmaxf(p1raw[(size_t)m * 256 + k0 + kk] + b1[k0 + kk], 0.f);
  }
  __syncthreads();
  const int n = tid & 31, mg = tid >> 5;
  const int ng = n0 + n;
  if (ng >= NT_DIM) return;
  float acc[4];
#pragma unroll
  for (int mi = 0; mi < 4; ++mi) acc[mi] = (blockIdx.y == 0) ? b2[ng] : 0.f;
#pragma unroll 8
  for (int kk = 0; kk < 32; ++kk) {
    float w = W2[(size_t)(k0 + kk) * NT_DIM + ng];
#pragma unroll
    for (int mi = 0; mi < 4; ++mi)
      acc[mi] = fmaf(ps[mg * 4 + mi][kk], w, acc[mi]);
  }
#pragma unroll
  for (int mi = 0; mi < 4; ++mi)
    atomicAdd(&out[(size_t)(mg * 4 + mi) * NT_DIM + ng], acc[mi]);
}

// ---------------------------------------------------------------------------
extern "C" void kernel_launch(void* const* d_in, const int* in_sizes, int n_in,
                              void* d_out, int out_size, void* d_ws, size_t ws_size,
                              hipStream_t stream)
{
  const float* x       = (const float*)d_in[0];
  const float* embed_w = (const float*)d_in[1];
  const float* embed_b = (const float*)d_in[2];
  const float* qkvo_w  = (const float*)d_in[3];
  const float* qkvo_b  = (const float*)d_in[4];
  const float* ffn_w1  = (const float*)d_in[5];
  const float* ffn_b1  = (const float*)d_in[6];
  const float* ffn_w2  = (const float*)d_in[7];
  const float* ffn_b2  = (const float*)d_in[8];
  const float* proj_w1 = (const float*)d_in[9];
  const float* proj_b1 = (const float*)d_in[10];
  const float* proj_w2 = (const float*)d_in[11];
  const float* proj_b2 = (const float*)d_in[12];
  float* out = (float*)d_out;

  float* ws = (float*)d_ws;
  // slots: 0 = Vb bf16 / Hb half; 1 = Hb half; 2 = xb -> QKh fp16T -> Yb bf16;
  //        3 = Xb bf16 trunk (x / h)
  float* Bv = ws;
  float* Bq = ws + 2 * SZ;
  float* Bk = ws + 3 * SZ;
  ushortT* Sb = (ushortT*)(ws + 4 * SZ);            // bf16 scratch (x1 / attn)
  ushortT* Wb = (ushortT*)(ws + 4 * SZ + SZ / 2);   // bf16 weights
  ushortT* embed_wt = Wb;                            // [512][256]
  ushortT* qkvo_wt  = embed_wt + (size_t)512 * 256;  // 8 x [512][512]
  ushortT* ffn1_wt  = qkvo_wt + (size_t)8 * 512 * 512;   // 2 x [2048][512]
  ushortT* ffn2_wt  = ffn1_wt + (size_t)2 * 2048 * 512;  // 2 x [512][2048]
  float* hm = (float*)(ffn2_wt + (size_t)2 * 512 * 2048); // [32][512]
  float* p1raw = hm + 16384;                               // [32][256]
  ushortT* Hb  = (ushortT*)Bv;   // FFN hidden bf16 [16384][2048] (slots 0+1)
  ushortT* Vb  = (ushortT*)Bv;   // V bf16 [16384][512]
  ushortT* xb  = (ushortT*)Bq;   // x bf16 during embed
  ushortT* QKh = (ushortT*)Bq;   // Qh [0,SZ) + Kh [SZ,2SZ) fp16T
  ushortT* Yb  = (ushortT*)Bq;   // y bf16 (after QKh dead)
  ushortT* Xb  = (ushortT*)Bk;   // trunk x bf16

  dim3 blk(256);

  hipMemsetAsync(hm, 0, 16384 * sizeof(float), stream);
  hipMemsetAsync(p1raw, 0, 8192 * sizeof(float), stream);
  hipMemsetAsync(out, 0, (size_t)B_DIM * NT_DIM * sizeof(float), stream);

  // weight conversions + x->bf16, one dispatch
  conv_all<<<dim3(16, 64, 14), blk, 0, stream>>>(
      embed_w, qkvo_w, ffn_w1, ffn_w2, x, xb,
      embed_wt, qkvo_wt, ffn1_wt, ffn2_wt);

  // embed: Xb(bf16) = x @ We + be
  gemm_bf16<0, 0, 2><<<dim3(4, 128), blk, 0, stream>>>(
      xb, embed_wt, embed_b, nullptr, nullptr, Xb, nullptr, nullptr,
      16384, IN_DIM, D_DIM);

  for (int l = 0; l < 2; ++l) {
    const ushortT* qw = qkvo_wt + (size_t)l * 4 * 512 * 512;
    const float* qb = qkvo_b + (size_t)l * 4 * 512;
    // fused QKV: Q -> QKh (fp16T), K -> QKh+SZ (fp16T), V -> Vb (bf16 plain)
    gemm_bf16<0, 0, 3><<<dim3(12, 128), blk, 0, stream>>>(
        Xb, qw, qb, nullptr, nullptr, Vb, QKh, QKh + SZ, 16384, 512, 1536);
    autocorr_fft<<<dim3(B_DIM * 64), dim3(512), 0, stream>>>(QKh, QKh + SZ, Vb, Sb);
    // y(bf16) = attn @ Wo + bo + x (bf16 res)  (QKh dead -> Yb)
    gemm_bf16<0, 2, 2><<<dim3(4, 128), blk, 0, stream>>>(
        Sb, qw + (size_t)3 * 512 * 512, qb + 1536, Xb, nullptr, Yb,
        nullptr, nullptr, 16384, 512, 512);
    // x1 = y - movavg(y) -> Sb
    movavg_bf16<0><<<dim3(16, 32), blk, 0, stream>>>(Yb, Sb, nullptr);
    // FFN (hidden bf16 overlays slots 0+1; V dead)
    gemm_bf16<1, 0, 2><<<dim3(16, 128), blk, 0, stream>>>(
        Sb, ffn1_wt + (size_t)l * 2048 * 512, ffn_b1 + (size_t)l * DFF_DIM,
        nullptr, nullptr, Hb, nullptr, nullptr, 16384, 512, 2048);
    gemm_bf16<0, 2, 2><<<dim3(4, 128), blk, 0, stream>>>(
        Hb, ffn2_wt + (size_t)l * 512 * 2048, ffn_b2 + (size_t)l * D_DIM,
        Sb, nullptr, Yb, nullptr, nullptr, 16384, 2048, 512);
    // x_next = y2 - movavg(y2) -> Xb (+ fused mean on last layer)
    if (l == 1)
      movavg_bf16<1><<<dim3(16, 32), blk, 0, stream>>>(Yb, Xb, hm);
    else
      movavg_bf16<0><<<dim3(16, 32), blk, 0, stream>>>(Yb, Xb, nullptr);
  }

  proj1_part<<<dim3(8, 16), blk, 0, stream>>>(hm, proj_w1, p1raw);
  proj2_part<<<dim3(14, 8), blk, 0, stream>>>(p1raw, proj_b1, proj_w2,
                                              proj_b2, out);
}